// Round 3
// baseline (824.772 us; speedup 1.0000x reference)
//
#include <hip/hip_runtime.h>

#define HW 3136      // 56*56
#define SHS 116      // sH row stride: 112 px + 4 pad

// Fused stage: grouped3x3 conv + bias + BN + ReLU -> (LDS) -> grouped1x1 conv
// + bias + BN + ReLU -> global.
// Block = (b, g, 2-row tile). g = pw group index = gconv conv-index i.
// LDS 46 KB -> 3 blocks/CU (12 waves) for latency hiding.
__global__ __launch_bounds__(256, 3) void fused_stage(
    const float* __restrict__ in,    // [32,256,56,56]
    const float* __restrict__ gw,    // [4,64,4,3,3]  (i,k,cc,dy,dx)
    const float* __restrict__ gb,    // [256] flat (i*64+k)
    const float* __restrict__ bnag, const float* __restrict__ bnab,
    const float* __restrict__ bnam, const float* __restrict__ bnav,
    const float* __restrict__ pw,    // [256,64]
    const float* __restrict__ pb,    // [256]
    const float* __restrict__ bnbg, const float* __restrict__ bnbb,
    const float* __restrict__ bnbm, const float* __restrict__ bnbv,
    float* __restrict__ out)         // [32,256,56,56]
{
    __shared__ __align__(16) float sH[64 * SHS];   // 29696 B
    __shared__ __align__(16) float sW[64 * 64];    // 16384 B   (total 46080)

    const int tid = threadIdx.x;
    const int blk = blockIdx.x;
    // XCD-aware swizzle: the 4 g-copies of one (b,t) input slab get dispatch
    // indices 8 apart -> same XCD (round-robin blk%8), adjacent in time ->
    // per-XCD L2 absorbs the 4x input re-read.
    const int x8 = blk & 7;
    const int r8 = blk >> 3;          // [0,448)
    const int g  = r8 & 3;
    const int s  = (r8 >> 2) * 8 + x8;// [0,896) = b*28 + t
    const int t  = s % 28;
    const int b  = s / 28;
    const int y0 = t * 2;

    // ---- phase 0: stage pw weights for group g, transposed to [c][o] ----
    {
        const int o  = tid & 63;
        const int c0 = (tid >> 6) * 16;
        const float* src = pw + (size_t)(g * 64 + o) * 64 + c0;
        float4 v0 = *(const float4*)(src + 0);
        float4 v1 = *(const float4*)(src + 4);
        float4 v2 = *(const float4*)(src + 8);
        float4 v3 = *(const float4*)(src + 12);
        float tmp[16] = {v0.x, v0.y, v0.z, v0.w, v1.x, v1.y, v1.z, v1.w,
                         v2.x, v2.y, v2.z, v2.w, v3.x, v3.y, v3.z, v3.w};
#pragma unroll
        for (int j = 0; j < 16; ++j)
            sW[(c0 + j) * 64 + o] = tmp[j];   // bank = o%32: 2-way (free)
    }

    // ---- phase 1: grouped 3x3 conv, conv-index g, all 64 groups k ----
    const int k  = tid >> 2;          // 0..63 (intermediate channel g*64+k)
    const int xs = tid & 3;
    const int x0 = xs * 14;

    float wr[36];                     // gw[g][k][*], contiguous, 16B-aligned
    {
        const float4* w4 = (const float4*)(gw + (size_t)(g * 64 + k) * 36);
#pragma unroll
        for (int j = 0; j < 9; ++j) {
            float4 v = w4[j];
            wr[4*j+0] = v.x; wr[4*j+1] = v.y; wr[4*j+2] = v.z; wr[4*j+3] = v.w;
        }
    }

    float acc[2][14];
#pragma unroll
    for (int r = 0; r < 2; ++r)
#pragma unroll
        for (int xx = 0; xx < 14; ++xx) acc[r][xx] = 0.f;

#pragma unroll
    for (int cc = 0; cc < 4; ++cc) {
        const float* chp = in + ((size_t)(b * 256 + k * 4 + cc)) * HW;
        float rw[4][16];              // rows y0-1..y0+2, cols x0-1..x0+14
#pragma unroll
        for (int ry = 0; ry < 4; ++ry) {
            const int gy = y0 - 1 + ry;              // block-uniform
            if ((unsigned)gy < 56u) {
                const float* rp = chp + gy * 56;
                rw[ry][0]  = (x0 > 0)       ? rp[x0 - 1]  : 0.f;
                rw[ry][15] = (x0 + 14 < 56) ? rp[x0 + 14] : 0.f;
#pragma unroll
                for (int j = 0; j < 7; ++j) {
                    float2 v = *(const float2*)(rp + x0 + 2 * j);
                    rw[ry][1 + 2*j] = v.x; rw[ry][2 + 2*j] = v.y;
                }
            } else {
#pragma unroll
                for (int j = 0; j < 16; ++j) rw[ry][j] = 0.f;
            }
        }
#pragma unroll
        for (int ry = 0; ry < 4; ++ry) {
            const int rlo = (ry >= 2) ? ry - 2 : 0;
            const int rhi = (ry <= 1) ? ry : 1;
#pragma unroll
            for (int rr = 0; rr < 2; ++rr) {
                if (rr < rlo || rr > rhi) continue;  // dead after unroll
                const int dy = ry - rr;
                const float w0 = wr[cc*9 + dy*3 + 0];
                const float w1 = wr[cc*9 + dy*3 + 1];
                const float w2 = wr[cc*9 + dy*3 + 2];
#pragma unroll
                for (int xx = 0; xx < 14; ++xx)
                    acc[rr][xx] = fmaf(w2, rw[ry][xx+2],
                                  fmaf(w1, rw[ry][xx+1],
                                  fmaf(w0, rw[ry][xx], acc[rr][xx])));
            }
        }
    }

    // bias + BN-a + ReLU -> sH[k][r*56+x]
    {
        const int c = g * 64 + k;
        const float sc = bnag[c] * rsqrtf(bnav[c] + 1e-5f);
        const float sh = fmaf(gb[c], sc, bnab[c] - bnam[c] * sc);
#pragma unroll
        for (int r = 0; r < 2; ++r)
#pragma unroll
            for (int j = 0; j < 7; ++j) {
                float v0 = fmaxf(fmaf(acc[r][2*j],   sc, sh), 0.f);
                float v1 = fmaxf(fmaf(acc[r][2*j+1], sc, sh), 0.f);
                *(float2*)&sH[k * SHS + r * 56 + x0 + 2*j] = make_float2(v0, v1);
            }
    }
    __syncthreads();

    // ---- phase 2: [64 out] x [112 px] = W[64x64] * sH[64x112] GEMM ----
    // thread tile: 2 out-ch x 14 px
    const int og = tid >> 3;          // 0..31 -> out channels og*2, og*2+1
    const int pg = tid & 7;           // 0..7  -> px pg*14..pg*14+13
    const int p0 = pg * 14;

    float a2[2][14];
#pragma unroll
    for (int i = 0; i < 2; ++i)
#pragma unroll
        for (int xx = 0; xx < 14; ++xx) a2[i][xx] = 0.f;

#pragma unroll 2
    for (int c = 0; c < 64; ++c) {
        const float2 wv = *(const float2*)&sW[c * 64 + og * 2]; // 8-lane bcast
        float hr[14];
#pragma unroll
        for (int j = 0; j < 7; ++j) {
            float2 v = *(const float2*)&sH[c * SHS + p0 + 2*j]; // 8-lane bcast
            hr[2*j] = v.x; hr[2*j+1] = v.y;
        }
#pragma unroll
        for (int xx = 0; xx < 14; ++xx) {
            a2[0][xx] = fmaf(wv.x, hr[xx], a2[0][xx]);
            a2[1][xx] = fmaf(wv.y, hr[xx], a2[1][xx]);
        }
    }

    // bias + BN-b + ReLU -> global (rows contiguous: y0*56 + p0 spans 2 rows)
#pragma unroll
    for (int i = 0; i < 2; ++i) {
        const int o = g * 64 + og * 2 + i;
        const float sc = bnbg[o] * rsqrtf(bnbv[o] + 1e-5f);
        const float sh = fmaf(pb[o], sc, bnbb[o] - bnbm[o] * sc);
        float* op = out + ((size_t)(b * 256 + o)) * HW + y0 * 56 + p0;
#pragma unroll
        for (int j = 0; j < 7; ++j) {
            float v0 = fmaxf(fmaf(a2[i][2*j],   sc, sh), 0.f);
            float v1 = fmaxf(fmaf(a2[i][2*j+1], sc, sh), 0.f);
            *(float2*)(op + 2*j) = make_float2(v0, v1);
        }
    }
}

extern "C" void kernel_launch(void* const* d_in, const int* in_sizes, int n_in,
                              void* d_out, int out_size, void* d_ws, size_t ws_size,
                              hipStream_t stream) {
    const float* x     = (const float*)d_in[0];
    const float* w1    = (const float*)d_in[1];
    const float* b1    = (const float*)d_in[2];
    const float* bn1ag = (const float*)d_in[3];
    const float* bn1ab = (const float*)d_in[4];
    const float* bn1am = (const float*)d_in[5];
    const float* bn1av = (const float*)d_in[6];
    const float* pw1   = (const float*)d_in[7];
    const float* pb1   = (const float*)d_in[8];
    const float* bn1bg = (const float*)d_in[9];
    const float* bn1bb = (const float*)d_in[10];
    const float* bn1bm = (const float*)d_in[11];
    const float* bn1bv = (const float*)d_in[12];
    const float* w2    = (const float*)d_in[13];
    const float* b2    = (const float*)d_in[14];
    const float* bn2ag = (const float*)d_in[15];
    const float* bn2ab = (const float*)d_in[16];
    const float* bn2am = (const float*)d_in[17];
    const float* bn2av = (const float*)d_in[18];
    const float* pw2   = (const float*)d_in[19];
    const float* pb2   = (const float*)d_in[20];
    const float* bn2bg = (const float*)d_in[21];
    const float* bn2bb = (const float*)d_in[22];
    const float* bn2bm = (const float*)d_in[23];
    const float* bn2bv = (const float*)d_in[24];

    float* mid  = (float*)d_ws;      // 32*256*56*56*4 = 102,760,448 B
    float* outp = (float*)d_out;

    const int grid = 32 * 4 * 28;    // 3584 blocks: (b, g, 2-row tile), swizzled

    fused_stage<<<grid, 256, 0, stream>>>(x,   w1, b1, bn1ag, bn1ab, bn1am, bn1av,
                                          pw1, pb1, bn1bg, bn1bb, bn1bm, bn1bv, mid);
    fused_stage<<<grid, 256, 0, stream>>>(mid, w2, b2, bn2ag, bn2ab, bn2am, bn2av,
                                          pw2, pb2, bn2bg, bn2bb, bn2bm, bn2bv, outp);
}